// Round 5
// baseline (424.227 us; speedup 1.0000x reference)
//
#include <hip/hip_runtime.h>

typedef __bf16 bf16_t;
typedef bf16_t bf16x8 __attribute__((ext_vector_type(8)));
typedef bf16_t bf16x4 __attribute__((ext_vector_type(4)));
typedef float floatx4 __attribute__((ext_vector_type(4)));
typedef unsigned short ushort_t;

#define HLD 264   // h_lds row stride in bf16 elems (256 + 8 pad)
#define OLD 68    // out_s / wfcc_s row stride in f32 (64 + 4 pad)

__device__ __forceinline__ floatx4 mfma16(bf16x8 a, bf16x8 b, floatx4 c) {
  return __builtin_amdgcn_mfma_f32_16x16x32_bf16(a, b, c, 0, 0, 0);
}

__device__ __forceinline__ float tanh_fast(float x) {
  x = fminf(15.0f, fmaxf(-15.0f, x));
  float e = __expf(-2.0f * x);
  return (1.0f - e) / (1.0f + e);
}

__device__ __forceinline__ bf16x8 cvt8(floatx4 f0, floatx4 f1) {
  bf16x8 r;
  r[0] = (bf16_t)f0[0]; r[1] = (bf16_t)f0[1]; r[2] = (bf16_t)f0[2]; r[3] = (bf16_t)f0[3];
  r[4] = (bf16_t)f1[0]; r[5] = (bf16_t)f1[1]; r[6] = (bf16_t)f1[2]; r[7] = (bf16_t)f1[3];
  return r;
}

// Pack weights (row-major [N][K] f32) into bf16 MFMA fragment order.
// frag (ntile, kstep): lane holds W[n = ntile*16 + (lane&15)][k = kstep*32 + (lane>>4)*8 + j]
// For mfma_16x16x32 the A-fragment (m = lane&15) and B-fragment (n = lane&15)
// have identical lane layouts, so this packing serves BOTH roles. The fused kernel
// uses it as the A operand (swapped multiply: D = W·h^T -> D[feat][batch]).
__global__ void pack_all(const float* __restrict__ Wh2h, const float* __restrict__ Wi2h,
                         const float* __restrict__ Wh2o, ushort_t* __restrict__ ws) {
  int id = blockIdx.x * 256 + threadIdx.x;
  const float* W; int ldk, ksteps; ushort_t* dst; int rel;
  if (id < 8192)       { W = Wh2h; ldk = 256; ksteps = 8; dst = ws;         rel = id; }
  else if (id < 10240) { W = Wi2h; ldk = 64;  ksteps = 2; dst = ws + 65536; rel = id - 8192; }
  else if (id < 12288) { W = Wh2o; ldk = 256; ksteps = 8; dst = ws + 81920; rel = id - 10240; }
  else return;
  int lane = rel & 63, fi = rel >> 6;
  int kstep = fi % ksteps, ntile = fi / ksteps;
  int n  = ntile * 16 + (lane & 15);
  int k0 = kstep * 32 + ((lane >> 4) << 3);
  const float* src = W + (size_t)n * ldk + k0;
  floatx4 f0 = *(const floatx4*)src;
  floatx4 f1 = *(const floatx4*)(src + 4);
  ((bf16x8*)dst)[rel] = cvt8(f0, f1);
}

// Fused RNN: 256 blocks x 512 threads; block owns 32 batch rows, all 16 steps.
//
// Round-5 configuration:
//  * ROLLED pair-loop (#pragma unroll 1, two step bodies ~6 KB << 32 KB I$).
//    Full unroll (R2/R3) was an I$-thrash disaster: 322 us vs 139 us.
//  * x loads PREFETCHED ONE STEP AHEAD, issued post-barrier BEFORE the step's
//    stores. vmcnt retires IN ORDER: with x(t+1) older than stores(t), the
//    x-consume wait at t+1 is vmcnt(~17) and resolves with stores still in
//    flight. (R4 issued x(t) after stores(t-1) -> every step's MFMA-I phase
//    waited for the previous step's full 16KB/wave store drain = the 2.2x
//    gap vs the ~62 us HBM floor.)
//  * No other vmcnt-forcing op in the loop: hc2..4 pass-through hoisted to
//    kernel end; fcc/out stores are fire-and-forget.
//  * Relaxed per-step barrier (s_waitcnt lgkmcnt(0) + s_barrier): only LDS
//    carries cross-wave deps; global stores are never re-read.
__global__ __launch_bounds__(512, 2)
void rnn_fused(const float* __restrict__ x,      // [16][8192][64]
               const float* __restrict__ hc1,    // [8192][256]
               const float* __restrict__ hc2,
               const float* __restrict__ hc3,
               const float* __restrict__ hc4,
               const float* __restrict__ b_i2h,
               const float* __restrict__ b_h2h,
               const float* __restrict__ b_h2o,
               const float* __restrict__ W_fcc,  // [8][64]
               const float* __restrict__ b_fcc,
               const ushort_t* __restrict__ wsW,
               float* __restrict__ out_seq,      // [16][8192][8]
               float* __restrict__ hc1_f,        // [8192][256]
               float* __restrict__ hc2_o,
               float* __restrict__ hc3_o,
               float* __restrict__ hc4_o,
               float* __restrict__ i2h_seq,      // [16][8192][256]
               float* __restrict__ h2h_seq) {    // [16][8192][256]
  __shared__ bf16_t h_lds[2][32 * HLD];  // double-buffered hidden state
  __shared__ float  out_s[2][32 * OLD];  // double-buffered h2o output (fcc pipelined)
  __shared__ float  wfcc_s[8 * OLD];

  const int tid  = threadIdx.x;
  const int lane = tid & 63;
  const int wv   = tid >> 6;
  const int q    = lane >> 4;
  const int c    = lane & 15;
  const int r0   = blockIdx.x * 32;

  const bf16x8* WH = (const bf16x8*)(wsW);          // [16][8][64]
  const bf16x8* WI = (const bf16x8*)(wsW + 65536);  // [16][2][64]
  const bf16x8* WO = (const bf16x8*)(wsW + 81920);  // [4][8][64]

  // swapped layout: per lane, feature = (n0+nl)*16 + q*4 + rg, batch = mb*16 + c
  const int n0 = wv * 2;
  const int mo = wv >> 2, no = wv & 3;
  const int fm = tid >> 3, fo = tid & 7;

  auto load_x = [&](int t, floatx4 (&xv)[2][4]) {
    const float* xt = x + ((size_t)t * 8192 + r0) * 64;
#pragma unroll
    for (int k = 0; k < 2; ++k) {
      const float* p0 = xt + (c)      * 64 + k * 32 + q * 8;
      const float* p1 = xt + (16 + c) * 64 + k * 32 + q * 8;
      xv[k][0] = *(const floatx4*)p0;  xv[k][1] = *(const floatx4*)(p0 + 4);
      xv[k][2] = *(const floatx4*)p1;  xv[k][3] = *(const floatx4*)(p1 + 4);
    }
  };

  // ---- prefetch x(0) FIRST: oldest in queue, latency hides under setup ----
  floatx4 xA[2][4], xB[2][4];
  load_x(0, xA);

  // stage h0 (bf16) into h_lds[0]
  for (int i = tid; i < 2048; i += 512) {
    int m = i >> 6, k4 = (i & 63) * 4;
    floatx4 v = *(const floatx4*)&hc1[(size_t)(r0 + m) * 256 + k4];
    h_lds[0][m * HLD + k4 + 0] = (bf16_t)v[0];
    h_lds[0][m * HLD + k4 + 1] = (bf16_t)v[1];
    h_lds[0][m * HLD + k4 + 2] = (bf16_t)v[2];
    h_lds[0][m * HLD + k4 + 3] = (bf16_t)v[3];
  }
  { int o = tid >> 6, i = tid & 63; if (tid < 512) wfcc_s[o * OLD + i] = W_fcc[tid]; }

  floatx4 bI4[2], bH4[2];
  bI4[0] = *(const floatx4*)&b_i2h[(n0)     * 16 + q * 4];
  bI4[1] = *(const floatx4*)&b_i2h[(n0 + 1) * 16 + q * 4];
  bH4[0] = *(const floatx4*)&b_h2h[(n0)     * 16 + q * 4];
  bH4[1] = *(const floatx4*)&b_h2h[(n0 + 1) * 16 + q * 4];
  const floatx4 bO4 = *(const floatx4*)&b_h2o[no * 16 + q * 4];
  const float bF = b_fcc[fo];

  // loop-invariant weight fragments in registers (A-operand role)
  bf16x8 wh[8][2], wi[2][2], wo[8];
#pragma unroll
  for (int k = 0; k < 8; ++k) {
    wh[k][0] = WH[((n0)     * 8 + k) * 64 + lane];
    wh[k][1] = WH[((n0 + 1) * 8 + k) * 64 + lane];
    wo[k]    = WO[(no * 8 + k) * 64 + lane];
  }
#pragma unroll
  for (int k = 0; k < 2; ++k) {
    wi[k][0] = WI[((n0)     * 2 + k) * 64 + lane];
    wi[k][1] = WI[((n0 + 1) * 2 + k) * 64 + lane];
  }

  __syncthreads();

  auto step = [&](int t, int p, floatx4 (&xcur)[2][4], floatx4 (&xnext)[2][4]) {
    const size_t bt = (size_t)t * 8192 + r0;

    // convert prefetched x (issued BEFORE stores(t-1): older in the vmcnt
    // queue, so this wait resolves without draining those stores)
    bf16x8 ax0[2], ax1[2];
#pragma unroll
    for (int k = 0; k < 2; ++k) {
      ax0[k] = cvt8(xcur[k][0], xcur[k][1]);
      ax1[k] = cvt8(xcur[k][2], xcur[k][3]);
    }

    floatx4 accH[2][2], accI[2][2];
#pragma unroll
    for (int a = 0; a < 2; ++a)
#pragma unroll
      for (int b = 0; b < 2; ++b) { accH[a][b] = (floatx4){0,0,0,0}; accI[a][b] = (floatx4){0,0,0,0}; }

#pragma unroll
    for (int k = 0; k < 8; ++k) {
      bf16x8 a0 = *(const bf16x8*)&h_lds[p][(c)      * HLD + k * 32 + q * 8];
      bf16x8 a1 = *(const bf16x8*)&h_lds[p][(16 + c) * HLD + k * 32 + q * 8];
      accH[0][0] = mfma16(wh[k][0], a0, accH[0][0]);
      accH[1][0] = mfma16(wh[k][0], a1, accH[1][0]);
      accH[0][1] = mfma16(wh[k][1], a0, accH[0][1]);
      accH[1][1] = mfma16(wh[k][1], a1, accH[1][1]);
    }
#pragma unroll
    for (int k = 0; k < 2; ++k) {
      accI[0][0] = mfma16(wi[k][0], ax0[k], accI[0][0]);
      accI[1][0] = mfma16(wi[k][0], ax1[k], accI[1][0]);
      accI[0][1] = mfma16(wi[k][1], ax0[k], accI[0][1]);
      accI[1][1] = mfma16(wi[k][1], ax1[k], accI[1][1]);
    }

    // biases in place (accI=vi, accH=vh stay live across the barrier),
    // h_new bf16 into the other LDS buffer: 4 consecutive feats = one b64 write
#pragma unroll
    for (int mb = 0; mb < 2; ++mb)
#pragma unroll
      for (int nl = 0; nl < 2; ++nl) {
        accI[mb][nl] += bI4[nl];
        accH[mb][nl] += bH4[nl];
        bf16x4 hv4;
#pragma unroll
        for (int rg = 0; rg < 4; ++rg)
          hv4[rg] = (bf16_t)tanh_fast(accI[mb][nl][rg] + accH[mb][nl][rg]);
        *(bf16x4*)&h_lds[1 - p][(mb * 16 + c) * HLD + (n0 + nl) * 16 + q * 4] = hv4;
      }

    // ---- relaxed barrier: order LDS only; global stores stay in flight ----
    asm volatile("s_waitcnt lgkmcnt(0)" ::: "memory");
    __builtin_amdgcn_s_barrier();
    asm volatile("" ::: "memory");

    // ---- prefetch next step's x BEFORE this step's stores (queue order!) ----
    if (t < 15) load_x(t + 1, xnext);

    // ---- NT float4 stores: fire-and-forget, 2 steps of slack to retire ----
#pragma unroll
    for (int mb = 0; mb < 2; ++mb)
#pragma unroll
      for (int nl = 0; nl < 2; ++nl) {
        size_t gi = (bt + mb * 16 + c) * 256 + (n0 + nl) * 16 + q * 4;
        __builtin_nontemporal_store(accI[mb][nl], (floatx4*)&i2h_seq[gi]);
        __builtin_nontemporal_store(accH[mb][nl], (floatx4*)&h2h_seq[gi]);
        if (t == 15) {
          floatx4 hf;
#pragma unroll
          for (int rg = 0; rg < 4; ++rg)
            hf[rg] = tanh_fast(accI[mb][nl][rg] + accH[mb][nl][rg]);
          __builtin_nontemporal_store(hf,
              (floatx4*)&hc1_f[(size_t)(r0 + mb * 16 + c) * 256 + (n0 + nl) * 16 + q * 4]);
        }
      }

    // fcc for step t-1 (out_s[1-p] written in phase B(t-1), fenced by this barrier)
    if (t > 0 && tid < 256) {
      float s = bF;
#pragma unroll
      for (int i4 = 0; i4 < 16; ++i4) {
        floatx4 a = *(const floatx4*)&out_s[1 - p][fm * OLD + i4 * 4];
        floatx4 w = *(const floatx4*)&wfcc_s[fo * OLD + i4 * 4];
        s += a[0]*w[0] + a[1]*w[1] + a[2]*w[2] + a[3]*w[3];
      }
      __builtin_nontemporal_store(s, &out_seq[((size_t)(t - 1) * 8192 + r0 + fm) * 8 + fo]);
    }

    // ---- phase B: h2o on h_new (h_lds[1-p], fenced by this step's barrier) ----
    floatx4 accO = (floatx4){0,0,0,0};
#pragma unroll
    for (int k = 0; k < 8; ++k) {
      bf16x8 a = *(const bf16x8*)&h_lds[1 - p][(mo * 16 + c) * HLD + k * 32 + q * 8];
      accO = mfma16(wo[k], a, accO);
    }
    {
      floatx4 ov = accO + bO4;
      floatx4 osv;
#pragma unroll
      for (int rg = 0; rg < 4; ++rg) osv[rg] = tanh_fast(ov[rg]);
      *(floatx4*)&out_s[p][(mo * 16 + c) * OLD + no * 16 + q * 4] = osv;
    }
  };

#pragma unroll 1
  for (int tt = 0; tt < 16; tt += 2) {
    step(tt,     0, xA, xB);
    step(tt + 1, 1, xB, xA);
  }

  __syncthreads();  // full fence once: drains all outstanding stores + LDS
  // fcc for step 15 (out_s[1])
  if (tid < 256) {
    float s = bF;
#pragma unroll
    for (int i4 = 0; i4 < 16; ++i4) {
      floatx4 a = *(const floatx4*)&out_s[1][fm * OLD + i4 * 4];
      floatx4 w = *(const floatx4*)&wfcc_s[fo * OLD + i4 * 4];
      s += a[0]*w[0] + a[1]*w[1] + a[2]*w[2] + a[3]*w[3];
    }
    __builtin_nontemporal_store(s, &out_seq[((size_t)15 * 8192 + r0 + fm) * 8 + fo]);
  }

  // ---- hc2..4 pass-through, ONCE at kernel end (no per-step vmcnt drain) ----
#pragma unroll 1
  for (int tensor = 0; tensor < 3; ++tensor) {
    const float* s = tensor == 0 ? hc2 : (tensor == 1 ? hc3 : hc4);
    float*       d = tensor == 0 ? hc2_o : (tensor == 1 ? hc3_o : hc4_o);
    const floatx4* sp = (const floatx4*)(s + (size_t)r0 * 256);
    floatx4*       dp = (floatx4*)(d + (size_t)r0 * 256);
#pragma unroll
    for (int j = 0; j < 4; ++j) {
      floatx4 v = sp[tid + j * 512];
      __builtin_nontemporal_store(v, dp + tid + j * 512);
    }
  }
}

extern "C" void kernel_launch(void* const* d_in, const int* in_sizes, int n_in,
                              void* d_out, int out_size, void* d_ws, size_t ws_size,
                              hipStream_t stream) {
  (void)in_sizes; (void)n_in; (void)out_size; (void)ws_size;
  const float* x     = (const float*)d_in[0];
  const float* hc1   = (const float*)d_in[2];
  const float* hc2   = (const float*)d_in[3];
  const float* hc3   = (const float*)d_in[4];
  const float* hc4   = (const float*)d_in[5];
  const float* W_i2h = (const float*)d_in[6];
  const float* b_i2h = (const float*)d_in[7];
  const float* W_h2h = (const float*)d_in[8];
  const float* b_h2h = (const float*)d_in[9];
  const float* W_h2o = (const float*)d_in[10];
  const float* b_h2o = (const float*)d_in[11];
  const float* W_fcc = (const float*)d_in[12];
  const float* b_fcc = (const float*)d_in[13];

  float* out     = (float*)d_out;
  float* out_seq = out;                   // [16,8192,8]
  float* hc1_f   = out + 1048576;         // [8192,256]
  float* hc2_o   = out + 3145728;
  float* hc3_o   = out + 5242880;
  float* hc4_o   = out + 7340032;
  float* i2h_seq = out + 9437184;         // [16,8192,256]
  float* h2h_seq = out + 42991616;        // [16,8192,256]

  ushort_t* ws = (ushort_t*)d_ws;

  pack_all<<<48, 256, 0, stream>>>(W_h2h, W_i2h, W_h2o, ws);
  rnn_fused<<<256, 512, 0, stream>>>(x, hc1, hc2, hc3, hc4,
                                     b_i2h, b_h2h, b_h2o, W_fcc, b_fcc,
                                     (const ushort_t*)ws,
                                     out_seq, hc1_f, hc2_o, hc3_o, hc4_o,
                                     i2h_seq, h2h_seq);
}

// Round 6
// 419.393 us; speedup vs baseline: 1.0115x; 1.0115x over previous
//
#include <hip/hip_runtime.h>

typedef __bf16 bf16_t;
typedef bf16_t bf16x8 __attribute__((ext_vector_type(8)));
typedef bf16_t bf16x4 __attribute__((ext_vector_type(4)));
typedef float floatx4 __attribute__((ext_vector_type(4)));
typedef unsigned short ushort_t;

#define HLD 264    // h_lds row stride in bf16 elems (256 + 8 pad)
#define OLD 68     // out_s / wfcc_s row stride in f32 (64 + 4 pad)
#define IOLD 264   // i2h_s/h2h_s staging row stride in f32 (256 + 8 pad, 4-way banks)

__device__ __forceinline__ floatx4 mfma16(bf16x8 a, bf16x8 b, floatx4 c) {
  return __builtin_amdgcn_mfma_f32_16x16x32_bf16(a, b, c, 0, 0, 0);
}

__device__ __forceinline__ float tanh_fast(float x) {
  x = fminf(15.0f, fmaxf(-15.0f, x));
  float e = __expf(-2.0f * x);
  return (1.0f - e) / (1.0f + e);
}

__device__ __forceinline__ bf16x8 cvt8(floatx4 f0, floatx4 f1) {
  bf16x8 r;
  r[0] = (bf16_t)f0[0]; r[1] = (bf16_t)f0[1]; r[2] = (bf16_t)f0[2]; r[3] = (bf16_t)f0[3];
  r[4] = (bf16_t)f1[0]; r[5] = (bf16_t)f1[1]; r[6] = (bf16_t)f1[2]; r[7] = (bf16_t)f1[3];
  return r;
}

// Pack weights (row-major [N][K] f32) into bf16 MFMA fragment order.
// frag (ntile, kstep): lane holds W[n = ntile*16 + (lane&15)][k = kstep*32 + (lane>>4)*8 + j]
__global__ void pack_all(const float* __restrict__ Wh2h, const float* __restrict__ Wi2h,
                         const float* __restrict__ Wh2o, ushort_t* __restrict__ ws) {
  int id = blockIdx.x * 256 + threadIdx.x;
  const float* W; int ldk, ksteps; ushort_t* dst; int rel;
  if (id < 8192)       { W = Wh2h; ldk = 256; ksteps = 8; dst = ws;         rel = id; }
  else if (id < 10240) { W = Wi2h; ldk = 64;  ksteps = 2; dst = ws + 65536; rel = id - 8192; }
  else if (id < 12288) { W = Wh2o; ldk = 256; ksteps = 8; dst = ws + 81920; rel = id - 10240; }
  else return;
  int lane = rel & 63, fi = rel >> 6;
  int kstep = fi % ksteps, ntile = fi / ksteps;
  int n  = ntile * 16 + (lane & 15);
  int k0 = kstep * 32 + ((lane >> 4) << 3);
  const float* src = W + (size_t)n * ldk + k0;
  floatx4 f0 = *(const floatx4*)src;
  floatx4 f1 = *(const floatx4*)(src + 4);
  ((bf16x8*)dst)[rel] = cvt8(f0, f1);
}

// Fused RNN: 256 blocks x 512 threads; block owns 32 batch rows, all 16 steps.
//
// Round-6: FULL-LINE GLOBAL STORES via LDS staging.
//   Evidence (R2/R3 counters): FETCH_SIZE 695 MB vs ~96 MB read ideal,
//   IDENTICAL for plain vs NT stores. The per-acc store pattern writes 64 B
//   segments (half a 128 B L2 line) -> every i2h/h2h line is fetched to merge
//   (RFO): ~256 MB of partial stores -> ~500 MB extra fetch. Fix: stage acc
//   f32 results in LDS, then each wave stores 1 KB CONTIGUOUS per instruction
//   (64 lanes x 16 B; the block's 32-row slab is contiguous in i2h/h2h).
//   Two lgkm-relaxed barriers per step: #1 fences h_lds + staging writes,
//   #2 fences staging reads before next step's overwrite.
// Carried forward: rolled pair-loop (I$), x prefetch-ahead issued before the
//   stores, NT stores, weights in registers, fcc software-pipelined.
__global__ __launch_bounds__(512, 2)
void rnn_fused(const float* __restrict__ x,      // [16][8192][64]
               const float* __restrict__ hc1,    // [8192][256]
               const float* __restrict__ hc2,
               const float* __restrict__ hc3,
               const float* __restrict__ hc4,
               const float* __restrict__ b_i2h,
               const float* __restrict__ b_h2h,
               const float* __restrict__ b_h2o,
               const float* __restrict__ W_fcc,  // [8][64]
               const float* __restrict__ b_fcc,
               const ushort_t* __restrict__ wsW,
               float* __restrict__ out_seq,      // [16][8192][8]
               float* __restrict__ hc1_f,        // [8192][256]
               float* __restrict__ hc2_o,
               float* __restrict__ hc3_o,
               float* __restrict__ hc4_o,
               float* __restrict__ i2h_seq,      // [16][8192][256]
               float* __restrict__ h2h_seq) {    // [16][8192][256]
  __shared__ bf16_t h_lds[2][32 * HLD];  // double-buffered hidden state
  __shared__ float  out_s[2][32 * OLD];  // double-buffered h2o output (fcc pipelined)
  __shared__ float  wfcc_s[8 * OLD];
  extern __shared__ float io_dyn[];      // 2 x 32 x IOLD f32 staging (66 KB dynamic)
  float* i2h_s = io_dyn;
  float* h2h_s = io_dyn + 32 * IOLD;

  const int tid  = threadIdx.x;
  const int lane = tid & 63;
  const int wv   = tid >> 6;
  const int q    = lane >> 4;
  const int c    = lane & 15;
  const int r0   = blockIdx.x * 32;

  const bf16x8* WH = (const bf16x8*)(wsW);          // [16][8][64]
  const bf16x8* WI = (const bf16x8*)(wsW + 65536);  // [16][2][64]
  const bf16x8* WO = (const bf16x8*)(wsW + 81920);  // [4][8][64]

  // swapped layout: per lane, feature = (n0+nl)*16 + q*4 + rg, batch = mb*16 + c
  const int n0 = wv * 2;
  const int mo = wv >> 2, no = wv & 3;
  const int fm = tid >> 3, fo = tid & 7;

  auto load_x = [&](int t, floatx4 (&xv)[2][4]) {
    const float* xt = x + ((size_t)t * 8192 + r0) * 64;
#pragma unroll
    for (int k = 0; k < 2; ++k) {
      const float* p0 = xt + (c)      * 64 + k * 32 + q * 8;
      const float* p1 = xt + (16 + c) * 64 + k * 32 + q * 8;
      xv[k][0] = *(const floatx4*)p0;  xv[k][1] = *(const floatx4*)(p0 + 4);
      xv[k][2] = *(const floatx4*)p1;  xv[k][3] = *(const floatx4*)(p1 + 4);
    }
  };

  // ---- prefetch x(0) FIRST: oldest in queue, latency hides under setup ----
  floatx4 xA[2][4], xB[2][4];
  load_x(0, xA);

  // stage h0 (bf16) into h_lds[0]
  for (int i = tid; i < 2048; i += 512) {
    int m = i >> 6, k4 = (i & 63) * 4;
    floatx4 v = *(const floatx4*)&hc1[(size_t)(r0 + m) * 256 + k4];
    h_lds[0][m * HLD + k4 + 0] = (bf16_t)v[0];
    h_lds[0][m * HLD + k4 + 1] = (bf16_t)v[1];
    h_lds[0][m * HLD + k4 + 2] = (bf16_t)v[2];
    h_lds[0][m * HLD + k4 + 3] = (bf16_t)v[3];
  }
  { int o = tid >> 6, i = tid & 63; if (tid < 512) wfcc_s[o * OLD + i] = W_fcc[tid]; }

  floatx4 bI4[2], bH4[2];
  bI4[0] = *(const floatx4*)&b_i2h[(n0)     * 16 + q * 4];
  bI4[1] = *(const floatx4*)&b_i2h[(n0 + 1) * 16 + q * 4];
  bH4[0] = *(const floatx4*)&b_h2h[(n0)     * 16 + q * 4];
  bH4[1] = *(const floatx4*)&b_h2h[(n0 + 1) * 16 + q * 4];
  const floatx4 bO4 = *(const floatx4*)&b_h2o[no * 16 + q * 4];
  const float bF = b_fcc[fo];

  // loop-invariant weight fragments in registers (A-operand role)
  bf16x8 wh[8][2], wi[2][2], wo[8];
#pragma unroll
  for (int k = 0; k < 8; ++k) {
    wh[k][0] = WH[((n0)     * 8 + k) * 64 + lane];
    wh[k][1] = WH[((n0 + 1) * 8 + k) * 64 + lane];
    wo[k]    = WO[(no * 8 + k) * 64 + lane];
  }
#pragma unroll
  for (int k = 0; k < 2; ++k) {
    wi[k][0] = WI[((n0)     * 2 + k) * 64 + lane];
    wi[k][1] = WI[((n0 + 1) * 2 + k) * 64 + lane];
  }

  __syncthreads();

  auto step = [&](int t, int p, floatx4 (&xcur)[2][4], floatx4 (&xnext)[2][4]) {
    const size_t bt = (size_t)t * 8192 + r0;

    bf16x8 ax0[2], ax1[2];
#pragma unroll
    for (int k = 0; k < 2; ++k) {
      ax0[k] = cvt8(xcur[k][0], xcur[k][1]);
      ax1[k] = cvt8(xcur[k][2], xcur[k][3]);
    }

    floatx4 accH[2][2], accI[2][2];
#pragma unroll
    for (int a = 0; a < 2; ++a)
#pragma unroll
      for (int b = 0; b < 2; ++b) { accH[a][b] = (floatx4){0,0,0,0}; accI[a][b] = (floatx4){0,0,0,0}; }

#pragma unroll
    for (int k = 0; k < 8; ++k) {
      bf16x8 a0 = *(const bf16x8*)&h_lds[p][(c)      * HLD + k * 32 + q * 8];
      bf16x8 a1 = *(const bf16x8*)&h_lds[p][(16 + c) * HLD + k * 32 + q * 8];
      accH[0][0] = mfma16(wh[k][0], a0, accH[0][0]);
      accH[1][0] = mfma16(wh[k][0], a1, accH[1][0]);
      accH[0][1] = mfma16(wh[k][1], a0, accH[0][1]);
      accH[1][1] = mfma16(wh[k][1], a1, accH[1][1]);
    }
#pragma unroll
    for (int k = 0; k < 2; ++k) {
      accI[0][0] = mfma16(wi[k][0], ax0[k], accI[0][0]);
      accI[1][0] = mfma16(wi[k][0], ax1[k], accI[1][0]);
      accI[0][1] = mfma16(wi[k][1], ax0[k], accI[0][1]);
      accI[1][1] = mfma16(wi[k][1], ax1[k], accI[1][1]);
    }

    // biases; h_new bf16 -> other h_lds buffer; acc f32 -> LDS staging (b128)
#pragma unroll
    for (int mb = 0; mb < 2; ++mb)
#pragma unroll
      for (int nl = 0; nl < 2; ++nl) {
        accI[mb][nl] += bI4[nl];
        accH[mb][nl] += bH4[nl];
        bf16x4 hv4;
#pragma unroll
        for (int rg = 0; rg < 4; ++rg)
          hv4[rg] = (bf16_t)tanh_fast(accI[mb][nl][rg] + accH[mb][nl][rg]);
        *(bf16x4*)&h_lds[1 - p][(mb * 16 + c) * HLD + (n0 + nl) * 16 + q * 4] = hv4;
        int si = (mb * 16 + c) * IOLD + (n0 + nl) * 16 + q * 4;
        *(floatx4*)&i2h_s[si] = accI[mb][nl];
        *(floatx4*)&h2h_s[si] = accH[mb][nl];
        if (t == 15) {
          floatx4 hf;
#pragma unroll
          for (int rg = 0; rg < 4; ++rg)
            hf[rg] = tanh_fast(accI[mb][nl][rg] + accH[mb][nl][rg]);
          __builtin_nontemporal_store(hf,
              (floatx4*)&hc1_f[(size_t)(r0 + mb * 16 + c) * 256 + (n0 + nl) * 16 + q * 4]);
        }
      }

    // ---- barrier #1: LDS-only fence (h_lds + staging writes visible) ----
    asm volatile("s_waitcnt lgkmcnt(0)" ::: "memory");
    __builtin_amdgcn_s_barrier();
    asm volatile("" ::: "memory");

    // ---- prefetch next step's x BEFORE this step's stores (queue order) ----
    if (t < 15) load_x(t + 1, xnext);

    // ---- cooperative FULL-LINE stores: 1 KB contiguous per wave-instr ----
    {
      const size_t gfl = bt * 256;  // block slab start (float idx), rows contiguous
#pragma unroll
      for (int j = 0; j < 4; ++j) {
        int row = (wv << 2) + j;
        int src = row * IOLD + (lane << 2);
        size_t dst = gfl + ((size_t)row << 8) + (lane << 2);
        __builtin_nontemporal_store(*(const floatx4*)&i2h_s[src], (floatx4*)&i2h_seq[dst]);
        __builtin_nontemporal_store(*(const floatx4*)&h2h_s[src], (floatx4*)&h2h_seq[dst]);
      }
    }

    // fcc for step t-1 (out_s[1-p] written in phase B(t-1))
    if (t > 0 && tid < 256) {
      float s = bF;
#pragma unroll
      for (int i4 = 0; i4 < 16; ++i4) {
        floatx4 a = *(const floatx4*)&out_s[1 - p][fm * OLD + i4 * 4];
        floatx4 w = *(const floatx4*)&wfcc_s[fo * OLD + i4 * 4];
        s += a[0]*w[0] + a[1]*w[1] + a[2]*w[2] + a[3]*w[3];
      }
      __builtin_nontemporal_store(s, &out_seq[((size_t)(t - 1) * 8192 + r0 + fm) * 8 + fo]);
    }

    // ---- phase B: h2o on h_new (h_lds[1-p]) ----
    floatx4 accO = (floatx4){0,0,0,0};
#pragma unroll
    for (int k = 0; k < 8; ++k) {
      bf16x8 a = *(const bf16x8*)&h_lds[1 - p][(mo * 16 + c) * HLD + k * 32 + q * 8];
      accO = mfma16(wo[k], a, accO);
    }
    {
      floatx4 ov = accO + bO4;
      floatx4 osv;
#pragma unroll
      for (int rg = 0; rg < 4; ++rg) osv[rg] = tanh_fast(ov[rg]);
      *(floatx4*)&out_s[p][(mo * 16 + c) * OLD + no * 16 + q * 4] = osv;
    }

    // ---- barrier #2: staging reads done before next step overwrites ----
    asm volatile("s_waitcnt lgkmcnt(0)" ::: "memory");
    __builtin_amdgcn_s_barrier();
    asm volatile("" ::: "memory");
  };

#pragma unroll 1
  for (int tt = 0; tt < 16; tt += 2) {
    step(tt,     0, xA, xB);
    step(tt + 1, 1, xB, xA);
  }

  __syncthreads();  // full fence: drains all outstanding stores + LDS
  // fcc for step 15 (out_s[1])
  if (tid < 256) {
    float s = bF;
#pragma unroll
    for (int i4 = 0; i4 < 16; ++i4) {
      floatx4 a = *(const floatx4*)&out_s[1][fm * OLD + i4 * 4];
      floatx4 w = *(const floatx4*)&wfcc_s[fo * OLD + i4 * 4];
      s += a[0]*w[0] + a[1]*w[1] + a[2]*w[2] + a[3]*w[3];
    }
    __builtin_nontemporal_store(s, &out_seq[((size_t)15 * 8192 + r0 + fm) * 8 + fo]);
  }

  // ---- hc2..4 pass-through, ONCE at kernel end (full-line, contiguous) ----
#pragma unroll 1
  for (int tensor = 0; tensor < 3; ++tensor) {
    const float* s = tensor == 0 ? hc2 : (tensor == 1 ? hc3 : hc4);
    float*       d = tensor == 0 ? hc2_o : (tensor == 1 ? hc3_o : hc4_o);
    const floatx4* sp = (const floatx4*)(s + (size_t)r0 * 256);
    floatx4*       dp = (floatx4*)(d + (size_t)r0 * 256);
#pragma unroll
    for (int j = 0; j < 4; ++j) {
      floatx4 v = sp[tid + j * 512];
      __builtin_nontemporal_store(v, dp + tid + j * 512);
    }
  }
}

extern "C" void kernel_launch(void* const* d_in, const int* in_sizes, int n_in,
                              void* d_out, int out_size, void* d_ws, size_t ws_size,
                              hipStream_t stream) {
  (void)in_sizes; (void)n_in; (void)out_size; (void)ws_size;
  const float* x     = (const float*)d_in[0];
  const float* hc1   = (const float*)d_in[2];
  const float* hc2   = (const float*)d_in[3];
  const float* hc3   = (const float*)d_in[4];
  const float* hc4   = (const float*)d_in[5];
  const float* W_i2h = (const float*)d_in[6];
  const float* b_i2h = (const float*)d_in[7];
  const float* W_h2h = (const float*)d_in[8];
  const float* b_h2h = (const float*)d_in[9];
  const float* W_h2o = (const float*)d_in[10];
  const float* b_h2o = (const float*)d_in[11];
  const float* W_fcc = (const float*)d_in[12];
  const float* b_fcc = (const float*)d_in[13];

  float* out     = (float*)d_out;
  float* out_seq = out;                   // [16,8192,8]
  float* hc1_f   = out + 1048576;         // [8192,256]
  float* hc2_o   = out + 3145728;
  float* hc3_o   = out + 5242880;
  float* hc4_o   = out + 7340032;
  float* i2h_seq = out + 9437184;         // [16,8192,256]
  float* h2h_seq = out + 42991616;        // [16,8192,256]

  ushort_t* ws = (ushort_t*)d_ws;

  pack_all<<<48, 256, 0, stream>>>(W_h2h, W_i2h, W_h2o, ws);
  rnn_fused<<<256, 512, 2 * 32 * IOLD * sizeof(float), stream>>>(
      x, hc1, hc2, hc3, hc4,
      b_i2h, b_h2h, b_h2o, W_fcc, b_fcc,
      (const ushort_t*)ws,
      out_seq, hc1_f, hc2_o, hc3_o, hc4_o,
      i2h_seq, h2h_seq);
}